// Round 6
// baseline (325.503 us; speedup 1.0000x reference)
//
#include <hip/hip_runtime.h>

typedef __attribute__((ext_vector_type(8))) short bf16x8;
typedef __attribute__((ext_vector_type(4))) float f32x4;

#define MFMA16(a, b, c) __builtin_amdgcn_mfma_f32_16x16x32_bf16(a, b, c, 0, 0, 0)

__device__ __forceinline__ unsigned short f2bf(float f) {
    union { float f; unsigned u; } v; v.f = f;
    unsigned r = v.u + 0x7FFFu + ((v.u >> 16) & 1u);
    return (unsigned short)(r >> 16);
}

typedef __attribute__((address_space(1))) const unsigned char gas1;
typedef __attribute__((address_space(3))) unsigned char las3;
__device__ __forceinline__ void gload_lds16(const void* g, void* s) {
    __builtin_amdgcn_global_load_lds((gas1*)g, (las3*)s, 16, 0, 0);
}

// ---------------- X fp32 -> bf16 (vectorized) ----------------
__global__ void k_conv(const float* __restrict__ in, unsigned short* __restrict__ out, int n4) {
    int i = blockIdx.x * blockDim.x + threadIdx.x;
    if (i >= n4) return;
    float4 v = ((const float4*)in)[i];
    uint2 o;
    o.x = (unsigned)f2bf(v.x) | ((unsigned)f2bf(v.y) << 16);
    o.y = (unsigned)f2bf(v.z) | ((unsigned)f2bf(v.w) << 16);
    ((uint2*)out)[i] = o;
}

// ---------------- W fp32 [R][C] -> bf16 [C][R] (LDS tiled transpose) ----------------
__global__ void k_transpose(const float* __restrict__ in, unsigned short* __restrict__ out, int R, int C) {
    __shared__ float tile[32][33];
    int bx = blockIdx.x * 32, by = blockIdx.y * 32;
    int tx = threadIdx.x, ty = threadIdx.y;
    #pragma unroll
    for (int j = 0; j < 32; j += 8)
        tile[ty + j][tx] = in[(size_t)(by + ty + j) * C + bx + tx];
    __syncthreads();
    #pragma unroll
    for (int j = 0; j < 32; j += 8)
        out[(size_t)(bx + ty + j) * R + by + tx] = f2bf(tile[tx][ty + j]);
}

// ---------------- GEMM (m97 structure): C[M][N] = A[M][K] * Bt[N][K], bf16 in fp32 out ----
__global__ __launch_bounds__(256) void k_gemm(const unsigned short* __restrict__ A,
                                              const unsigned short* __restrict__ Bt,
                                              float* __restrict__ C, int M, int N, int K) {
    __shared__ __align__(16) unsigned short As[128 * 32];
    __shared__ __align__(16) unsigned short Bs[128 * 32];
    int t = threadIdx.x, w = t >> 6, l = t & 63, g = l >> 4, lr = l & 15;
    int m0 = blockIdx.y * 128, n0 = blockIdx.x * 128;
    int wm = (w >> 1) * 64, wn = (w & 1) * 64;
    f32x4 acc[4][4] = {};
    int c0 = w * 2, c1 = w * 2 + 1;
    int srow0 = c0 * 16 + (l >> 2), srow1 = c1 * 16 + (l >> 2);
    int scol = (l & 3) * 8;
    const unsigned short* Ag0 = A + (size_t)(m0 + srow0) * K + scol;
    const unsigned short* Ag1 = A + (size_t)(m0 + srow1) * K + scol;
    const unsigned short* Bg0 = Bt + (size_t)(n0 + srow0) * K + scol;
    const unsigned short* Bg1 = Bt + (size_t)(n0 + srow1) * K + scol;
    unsigned short* Ad0 = As + c0 * 512;
    unsigned short* Ad1 = As + c1 * 512;
    unsigned short* Bd0 = Bs + c0 * 512;
    unsigned short* Bd1 = Bs + c1 * 512;
    for (int k0 = 0; k0 < K; k0 += 32) {
        __syncthreads();
        gload_lds16(Ag0 + k0, Ad0);
        gload_lds16(Ag1 + k0, Ad1);
        gload_lds16(Bg0 + k0, Bd0);
        gload_lds16(Bg1 + k0, Bd1);
        __syncthreads();
        bf16x8 af[4], bfr[4];
        #pragma unroll
        for (int f = 0; f < 4; ++f) {
            af[f] = *(const bf16x8*)(As + (wm + f * 16 + lr) * 32 + g * 8);
            bfr[f] = *(const bf16x8*)(Bs + (wn + f * 16 + lr) * 32 + g * 8);
        }
        #pragma unroll
        for (int mf = 0; mf < 4; ++mf)
            #pragma unroll
            for (int nf = 0; nf < 4; ++nf)
                acc[mf][nf] = MFMA16(af[mf], bfr[nf], acc[mf][nf]);
    }
    #pragma unroll
    for (int mf = 0; mf < 4; ++mf)
        #pragma unroll
        for (int nf = 0; nf < 4; ++nf)
            #pragma unroll
            for (int r = 0; r < 4; ++r)
                C[(size_t)(m0 + wm + mf * 16 + g * 4 + r) * N + (n0 + wn + nf * 16 + lr)] = acc[mf][nf][r];
}

// ---------------- bias + RoPE + layout pack ----------------
__global__ void k_pack(const float* __restrict__ Y, const float* __restrict__ bq,
                       const float* __restrict__ bk, const float* __restrict__ bv,
                       const float* __restrict__ cosp, const float* __restrict__ sinp,
                       unsigned short* __restrict__ Qb, unsigned short* __restrict__ Kb,
                       unsigned short* __restrict__ Vt) {
    const int S = 2048;
    int row = blockIdx.x;      // b*S + s
    int hh = blockIdx.y;       // 0..15 Q, 16..17 K, 18..19 V
    int d = threadIdx.x;       // 0..127
    int b = row >> 11, s = row & 2047;
    const float* yrow = Y + (size_t)row * 2560;
    if (hh < 16) {
        const float* base = yrow + hh * 128;
        const float* bias = bq + hh * 128;
        float self = base[d] + bias[d];
        int pd = (d < 64) ? d + 64 : d - 64;
        float partner = base[pd] + bias[pd];
        float rot = (d < 64) ? -partner : partner;
        float c = cosp[(size_t)row * 128 + d];
        float sn = sinp[(size_t)row * 128 + d];
        float q = (self * c + rot * sn) * 0.08838834764831845f;
        Qb[((size_t)(b * 16 + hh) * S + s) * 128 + d] = f2bf(q);
    } else if (hh < 18) {
        int kv = hh - 16;
        const float* base = yrow + 2048 + kv * 128;
        const float* bias = bk + kv * 128;
        float self = base[d] + bias[d];
        int pd = (d < 64) ? d + 64 : d - 64;
        float partner = base[pd] + bias[pd];
        float rot = (d < 64) ? -partner : partner;
        float c = cosp[(size_t)row * 128 + d];
        float sn = sinp[(size_t)row * 128 + d];
        float k = self * c + rot * sn;
        Kb[((size_t)(b * 2 + kv) * S + s) * 128 + d] = f2bf(k);
    } else {
        int kv = hh - 18;
        float v = yrow[2304 + kv * 128 + d] + bv[kv * 128 + d];
        Vt[((size_t)(b * 2 + kv) * 128 + d) * S + s] = f2bf(v);
    }
}

// ---------------- flash attention v5: 32 q-rows/wave, q-tile 128, 256 blocks ----------------
// Each kf/vf LDS read feeds 2 MFMAs (2 q-frags in registers) -> LDS-pipe cost per output halved.
// 256 blocks: 8 pairs (p,15-p) x 16 h x 2 b, XCD-grouped; 34 kv-tiles per block (balanced).
#define PSTR 68
__global__ __launch_bounds__(256, 1) void k_attn(const unsigned short* __restrict__ Qb,
                                                 const unsigned short* __restrict__ Kb,
                                                 const unsigned short* __restrict__ Vt,
                                                 unsigned short* __restrict__ Ob) {
    const int S = 2048;
    __shared__ __align__(16) unsigned short Ks[2 * 64 * 128];
    __shared__ __align__(16) unsigned short Vs[2 * 128 * 64];
    __shared__ __align__(16) unsigned short Pw[4][32 * PSTR];
    int bid = blockIdx.x;
    int xcd = bid & 7, j = bid >> 3;      // j 0..31
    int pair = j & 7;                      // 0..7
    int G = (j >> 3) * 8 + xcd;            // 0..31: (h,b) group, all its pair-blocks on one XCD
    int h = G & 15, b = G >> 4;
    int kvh = h >> 3;
    int t = threadIdx.x, w = t >> 6, l = t & 63, g = l >> 4, lr = l & 15;
    int xk = lr & 7;
    const unsigned short* Kp = Kb + (size_t)(b * 2 + kvh) * S * 128;
    const unsigned short* Vp = Vt + (size_t)(b * 2 + kvh) * 128 * S;
    // staging geometry: 16 chunks of 1KB each for K and V; wave w owns chunks w*4..w*4+3
    int koff[4], voff[4], ldst[4];
    #pragma unroll
    for (int jj = 0; jj < 4; ++jj) {
        int c = w * 4 + jj;
        int r = c * 4 + (l >> 4);            // K row 0..63
        int ks = (l & 15) ^ (r & 7);         // pre-swizzled source slot
        koff[jj] = r * 128 + ks * 8;
        int rv = c * 8 + (l >> 3);           // V row (d) 0..127
        int vs = (l & 7) ^ (rv & 7);
        voff[jj] = rv * S + vs * 8;
        ldst[jj] = c * 512;
    }
    int cur = 0;
    #pragma unroll
    for (int half = 0; half < 2; ++half) {
        int qt = half == 0 ? pair : 15 - pair;   // q-tile of 128 rows
        const unsigned short* Qp = Qb + ((size_t)(b * 16 + h) * S + qt * 128 + w * 32) * 128;
        bf16x8 qf[2][4];
        #pragma unroll
        for (int qs = 0; qs < 2; ++qs)
            #pragma unroll
            for (int ch = 0; ch < 4; ++ch)
                qf[qs][ch] = *(const bf16x8*)(Qp + (qs * 16 + lr) * 128 + ch * 32 + g * 8);
        f32x4 oacc[2][8] = {};
        float m_r[2][4] = {{-3e38f, -3e38f, -3e38f, -3e38f}, {-3e38f, -3e38f, -3e38f, -3e38f}};
        float l_r[2][4] = {{0.f, 0.f, 0.f, 0.f}, {0.f, 0.f, 0.f, 0.f}};
        int qlo = qt * 128 + w * 32;
        int nkt = 2 * qt + 2;
        // prologue: stage tile 0 into buffer `cur`
        #pragma unroll
        for (int jj = 0; jj < 4; ++jj) {
            gload_lds16(Kp + koff[jj], Ks + cur * 8192 + ldst[jj]);
            gload_lds16(Vp + voff[jj], Vs + cur * 8192 + ldst[jj]);
        }
        __syncthreads();
        for (int kt = 0; kt < nkt; ++kt) {
            int k0 = kt * 64;
            if (kt + 1 < nkt) {
                const unsigned short* kb = Kp + (size_t)(k0 + 64) * 128;
                const unsigned short* vb = Vp + (size_t)(k0 + 64);
                unsigned short* kd = Ks + (cur ^ 1) * 8192;
                unsigned short* vd = Vs + (cur ^ 1) * 8192;
                #pragma unroll
                for (int jj = 0; jj < 4; ++jj) {
                    gload_lds16(kb + koff[jj], kd + ldst[jj]);
                    gload_lds16(vb + voff[jj], vd + ldst[jj]);
                }
            }
            const unsigned short* Kc = Ks + cur * 8192;
            const unsigned short* Vc = Vs + cur * 8192;
            bool active = (k0 <= qlo + 31);      // any unmasked k for this wave's rows?
            if (active) {
                // ---- S = Q K^T (each kf read feeds 2 MFMAs) ----
                f32x4 sacc[2][4] = {};
                __builtin_amdgcn_s_setprio(1);
                #pragma unroll
                for (int nf = 0; nf < 4; ++nf) {
                    int row = nf * 16 + lr;
                    #pragma unroll
                    for (int ch = 0; ch < 4; ++ch) {
                        bf16x8 kf = *(const bf16x8*)(Kc + row * 128 + (((ch * 4 + g) ^ xk) << 3));
                        sacc[0][nf] = MFMA16(qf[0][ch], kf, sacc[0][nf]);
                        sacc[1][nf] = MFMA16(qf[1][ch], kf, sacc[1][nf]);
                    }
                }
                __builtin_amdgcn_s_setprio(0);
                // ---- online softmax (mask only near the diagonal) ----
                bool diag = (k0 + 63 > qlo);
                #pragma unroll
                for (int qs = 0; qs < 2; ++qs) {
                    #pragma unroll
                    for (int r = 0; r < 4; ++r) {
                        int qg = qlo + qs * 16 + g * 4 + r;
                        float s0 = sacc[qs][0][r], s1 = sacc[qs][1][r];
                        float s2 = sacc[qs][2][r], s3 = sacc[qs][3][r];
                        if (diag) {
                            if (k0 + lr > qg) s0 = -1e30f;
                            if (k0 + 16 + lr > qg) s1 = -1e30f;
                            if (k0 + 32 + lr > qg) s2 = -1e30f;
                            if (k0 + 48 + lr > qg) s3 = -1e30f;
                        }
                        float mx = fmaxf(fmaxf(s0, s1), fmaxf(s2, s3));
                        mx = fmaxf(mx, __shfl_xor(mx, 1));
                        mx = fmaxf(mx, __shfl_xor(mx, 2));
                        mx = fmaxf(mx, __shfl_xor(mx, 4));
                        mx = fmaxf(mx, __shfl_xor(mx, 8));
                        float mnew = fmaxf(m_r[qs][r], mx);
                        float alpha = __expf(m_r[qs][r] - mnew);
                        float p0 = __expf(s0 - mnew), p1 = __expf(s1 - mnew);
                        float p2 = __expf(s2 - mnew), p3 = __expf(s3 - mnew);
                        float rs = (p0 + p1) + (p2 + p3);
                        rs += __shfl_xor(rs, 1);
                        rs += __shfl_xor(rs, 2);
                        rs += __shfl_xor(rs, 4);
                        rs += __shfl_xor(rs, 8);
                        l_r[qs][r] = l_r[qs][r] * alpha + rs;
                        m_r[qs][r] = mnew;
                        int prow = (qs * 16 + g * 4 + r) * PSTR + lr;
                        Pw[w][prow]      = f2bf(p0);
                        Pw[w][prow + 16] = f2bf(p1);
                        Pw[w][prow + 32] = f2bf(p2);
                        Pw[w][prow + 48] = f2bf(p3);
                        #pragma unroll
                        for (int df = 0; df < 8; ++df) oacc[qs][df][r] *= alpha;
                    }
                }
                asm volatile("s_waitcnt lgkmcnt(0)" ::: "memory");
                __builtin_amdgcn_sched_barrier(0);
                // ---- O += P V (each vf read feeds 2 MFMAs) ----
                __builtin_amdgcn_s_setprio(1);
                #pragma unroll
                for (int ch2 = 0; ch2 < 2; ++ch2) {
                    bf16x8 pf0 = *(const bf16x8*)(&Pw[w][lr * PSTR + ch2 * 32 + g * 8]);
                    bf16x8 pf1 = *(const bf16x8*)(&Pw[w][(16 + lr) * PSTR + ch2 * 32 + g * 8]);
                    #pragma unroll
                    for (int df = 0; df < 8; ++df) {
                        int row = df * 16 + lr;
                        bf16x8 vf = *(const bf16x8*)(Vc + row * 64 + (((ch2 * 4 + g) ^ xk) << 3));
                        oacc[0][df] = MFMA16(pf0, vf, oacc[0][df]);
                        oacc[1][df] = MFMA16(pf1, vf, oacc[1][df]);
                    }
                }
                __builtin_amdgcn_s_setprio(0);
            }
            __syncthreads();
            cur ^= 1;
        }
        // ---- epilogue ----
        #pragma unroll
        for (int qs = 0; qs < 2; ++qs) {
            #pragma unroll
            for (int r = 0; r < 4; ++r) {
                float inv = 1.0f / l_r[qs][r];
                size_t orow = ((size_t)b * S + qt * 128 + w * 32 + qs * 16 + g * 4 + r) * 2048 + h * 128;
                #pragma unroll
                for (int df = 0; df < 8; ++df)
                    Ob[orow + df * 16 + lr] = f2bf(oacc[qs][df][r] * inv);
            }
        }
    }
}

extern "C" void kernel_launch(void* const* d_in, const int* in_sizes, int n_in,
                              void* d_out, int out_size, void* d_ws, size_t ws_size,
                              hipStream_t stream) {
    const float* X    = (const float*)d_in[0];
    const float* cosp = (const float*)d_in[1];
    const float* sinp = (const float*)d_in[2];
    // d_in[3] = attention_mask (exactly causal; implemented analytically)
    const float* Wq = (const float*)d_in[4];
    const float* bq = (const float*)d_in[5];
    const float* Wk = (const float*)d_in[6];
    const float* bk = (const float*)d_in[7];
    const float* Wv = (const float*)d_in[8];
    const float* bv = (const float*)d_in[9];
    const float* Wo = (const float*)d_in[10];
    float* Out = (float*)d_out;

    char* ws = (char*)d_ws;
    unsigned short* Xb  = (unsigned short*)(ws + 0);
    unsigned short* Wt  = (unsigned short*)(ws + 16777216);
    unsigned short* Wot = (unsigned short*)(ws + 27262976);
    float*          Yq  = (float*)(ws + 35651584);
    unsigned short* Qb  = (unsigned short*)(ws + 0);
    unsigned short* Kb  = (unsigned short*)(ws + 16777216);   // 2 MB
    unsigned short* Vtb = (unsigned short*)(ws + 18874368);   // 2 MB ([4][128][2048])
    unsigned short* Ab  = (unsigned short*)(ws + 35651584);

    k_conv<<<2097152 / 256, 256, 0, stream>>>(X, Xb, 2097152);
    dim3 tb(32, 8);
    k_transpose<<<dim3(64, 64), tb, 0, stream>>>(Wq, Wt, 2048, 2048);
    k_transpose<<<dim3(8, 64), tb, 0, stream>>>(Wk, Wt + (size_t)2048 * 2048, 2048, 256);
    k_transpose<<<dim3(8, 64), tb, 0, stream>>>(Wv, Wt + (size_t)2304 * 2048, 2048, 256);
    k_transpose<<<dim3(64, 64), tb, 0, stream>>>(Wo, Wot, 2048, 2048);
    k_gemm<<<dim3(2560 / 128, 4096 / 128), 256, 0, stream>>>(Xb, Wt, Yq, 4096, 2560, 2048);
    k_pack<<<dim3(4096, 20), 128, 0, stream>>>(Yq, bq, bk, bv, cosp, sinp, Qb, Kb, Vtb);
    k_attn<<<dim3(256), 256, 0, stream>>>(Qb, Kb, Vtb, Ab);
    k_gemm<<<dim3(2048 / 128, 4096 / 128), 256, 0, stream>>>(Ab, Wot, Out, 4096, 2048, 2048);
}

// Round 7
// 315.068 us; speedup vs baseline: 1.0331x; 1.0331x over previous
//
#include <hip/hip_runtime.h>

typedef __attribute__((ext_vector_type(8))) short bf16x8;
typedef __attribute__((ext_vector_type(4))) float f32x4;

#define MFMA16(a, b, c) __builtin_amdgcn_mfma_f32_16x16x32_bf16(a, b, c, 0, 0, 0)

__device__ __forceinline__ unsigned short f2bf(float f) {
    union { float f; unsigned u; } v; v.f = f;
    unsigned r = v.u + 0x7FFFu + ((v.u >> 16) & 1u);
    return (unsigned short)(r >> 16);
}

typedef __attribute__((address_space(1))) const unsigned char gas1;
typedef __attribute__((address_space(3))) unsigned char las3;
__device__ __forceinline__ void gload_lds16(const void* g, void* s) {
    __builtin_amdgcn_global_load_lds((gas1*)g, (las3*)s, 16, 0, 0);
}

// ---------------- X fp32 -> bf16 (vectorized) ----------------
__global__ void k_conv(const float* __restrict__ in, unsigned short* __restrict__ out, int n4) {
    int i = blockIdx.x * blockDim.x + threadIdx.x;
    if (i >= n4) return;
    float4 v = ((const float4*)in)[i];
    uint2 o;
    o.x = (unsigned)f2bf(v.x) | ((unsigned)f2bf(v.y) << 16);
    o.y = (unsigned)f2bf(v.z) | ((unsigned)f2bf(v.w) << 16);
    ((uint2*)out)[i] = o;
}

// ---------------- W fp32 [R][C] -> bf16 [C][R] (LDS tiled transpose) ----------------
__global__ void k_transpose(const float* __restrict__ in, unsigned short* __restrict__ out, int R, int C) {
    __shared__ float tile[32][33];
    int bx = blockIdx.x * 32, by = blockIdx.y * 32;
    int tx = threadIdx.x, ty = threadIdx.y;
    #pragma unroll
    for (int j = 0; j < 32; j += 8)
        tile[ty + j][tx] = in[(size_t)(by + ty + j) * C + bx + tx];
    __syncthreads();
    #pragma unroll
    for (int j = 0; j < 32; j += 8)
        out[(size_t)(bx + ty + j) * R + by + tx] = f2bf(tile[tx][ty + j]);
}

// ---------------- GEMM (m97 structure): C[M][N] = A[M][K] * Bt[N][K], bf16 in fp32 out ----
__global__ __launch_bounds__(256) void k_gemm(const unsigned short* __restrict__ A,
                                              const unsigned short* __restrict__ Bt,
                                              float* __restrict__ C, int M, int N, int K) {
    __shared__ __align__(16) unsigned short As[128 * 32];
    __shared__ __align__(16) unsigned short Bs[128 * 32];
    int t = threadIdx.x, w = t >> 6, l = t & 63, g = l >> 4, lr = l & 15;
    int m0 = blockIdx.y * 128, n0 = blockIdx.x * 128;
    int wm = (w >> 1) * 64, wn = (w & 1) * 64;
    f32x4 acc[4][4] = {};
    int c0 = w * 2, c1 = w * 2 + 1;
    int srow0 = c0 * 16 + (l >> 2), srow1 = c1 * 16 + (l >> 2);
    int scol = (l & 3) * 8;
    const unsigned short* Ag0 = A + (size_t)(m0 + srow0) * K + scol;
    const unsigned short* Ag1 = A + (size_t)(m0 + srow1) * K + scol;
    const unsigned short* Bg0 = Bt + (size_t)(n0 + srow0) * K + scol;
    const unsigned short* Bg1 = Bt + (size_t)(n0 + srow1) * K + scol;
    unsigned short* Ad0 = As + c0 * 512;
    unsigned short* Ad1 = As + c1 * 512;
    unsigned short* Bd0 = Bs + c0 * 512;
    unsigned short* Bd1 = Bs + c1 * 512;
    for (int k0 = 0; k0 < K; k0 += 32) {
        __syncthreads();
        gload_lds16(Ag0 + k0, Ad0);
        gload_lds16(Ag1 + k0, Ad1);
        gload_lds16(Bg0 + k0, Bd0);
        gload_lds16(Bg1 + k0, Bd1);
        __syncthreads();
        bf16x8 af[4], bfr[4];
        #pragma unroll
        for (int f = 0; f < 4; ++f) {
            af[f] = *(const bf16x8*)(As + (wm + f * 16 + lr) * 32 + g * 8);
            bfr[f] = *(const bf16x8*)(Bs + (wn + f * 16 + lr) * 32 + g * 8);
        }
        #pragma unroll
        for (int mf = 0; mf < 4; ++mf)
            #pragma unroll
            for (int nf = 0; nf < 4; ++nf)
                acc[mf][nf] = MFMA16(af[mf], bfr[nf], acc[mf][nf]);
    }
    #pragma unroll
    for (int mf = 0; mf < 4; ++mf)
        #pragma unroll
        for (int nf = 0; nf < 4; ++nf)
            #pragma unroll
            for (int r = 0; r < 4; ++r)
                C[(size_t)(m0 + wm + mf * 16 + g * 4 + r) * N + (n0 + wn + nf * 16 + lr)] = acc[mf][nf][r];
}

// ---------------- bias + RoPE + layout pack ----------------
__global__ void k_pack(const float* __restrict__ Y, const float* __restrict__ bq,
                       const float* __restrict__ bk, const float* __restrict__ bv,
                       const float* __restrict__ cosp, const float* __restrict__ sinp,
                       unsigned short* __restrict__ Qb, unsigned short* __restrict__ Kb,
                       unsigned short* __restrict__ Vt) {
    const int S = 2048;
    int row = blockIdx.x;      // b*S + s
    int hh = blockIdx.y;       // 0..15 Q, 16..17 K, 18..19 V
    int d = threadIdx.x;       // 0..127
    int b = row >> 11, s = row & 2047;
    const float* yrow = Y + (size_t)row * 2560;
    if (hh < 16) {
        const float* base = yrow + hh * 128;
        const float* bias = bq + hh * 128;
        float self = base[d] + bias[d];
        int pd = (d < 64) ? d + 64 : d - 64;
        float partner = base[pd] + bias[pd];
        float rot = (d < 64) ? -partner : partner;
        float c = cosp[(size_t)row * 128 + d];
        float sn = sinp[(size_t)row * 128 + d];
        float q = (self * c + rot * sn) * 0.08838834764831845f;
        Qb[((size_t)(b * 16 + hh) * S + s) * 128 + d] = f2bf(q);
    } else if (hh < 18) {
        int kv = hh - 16;
        const float* base = yrow + 2048 + kv * 128;
        const float* bias = bk + kv * 128;
        float self = base[d] + bias[d];
        int pd = (d < 64) ? d + 64 : d - 64;
        float partner = base[pd] + bias[pd];
        float rot = (d < 64) ? -partner : partner;
        float c = cosp[(size_t)row * 128 + d];
        float sn = sinp[(size_t)row * 128 + d];
        float k = self * c + rot * sn;
        Kb[((size_t)(b * 2 + kv) * S + s) * 128 + d] = f2bf(k);
    } else {
        int kv = hh - 18;
        float v = yrow[2304 + kv * 128 + d] + bv[kv * 128 + d];
        Vt[((size_t)(b * 2 + kv) * 128 + d) * S + s] = f2bf(v);
    }
}

// ---------------- flash attention v7 ----------------
// 512 blocks, one 128-row q-tile each; complement dispatch balances CU pairs (qtA+qtB=15).
// 4 waves x 32 q-rows (2x LDS amortization); 2 blocks/CU (LDS 67.6KB).
// K dbuf + V single-buffer staged via global_load_lds; raw s_barrier + counted vmcnt
// (never an idle drain): per tile {issue V(t),K(t+1) | QK+softmax | vmcnt(4) bar | PV | vmcnt(0) bar}.
#define PSTR 72
__global__ __launch_bounds__(256, 2) void k_attn(const unsigned short* __restrict__ Qb,
                                                 const unsigned short* __restrict__ Kb,
                                                 const unsigned short* __restrict__ Vt,
                                                 unsigned short* __restrict__ Ob) {
    const int S = 2048;
    __shared__ __align__(16) unsigned short Ks[2 * 64 * 128];   // 32 KB (double-buffered)
    __shared__ __align__(16) unsigned short Vs[128 * 64];       // 16 KB (single)
    __shared__ __align__(16) unsigned short Pw[4][32 * PSTR];   // 18 KB
    int bid = blockIdx.x;
    // complement dispatch: bids 0..255 -> qt 8..15 (long), 256..511 -> qt 7..0 (short);
    // round-robin XCD placement pairs CU slot c with c+256 => qtA+qtB = 15 (34 tiles/CU).
    int halfg = bid >> 8, idx = bid & 255;
    int qlevel = idx >> 5, i = idx & 31;
    int qt = halfg ? (7 - qlevel) : (8 + qlevel);
    // i = hsub*4 + kvg: xcd = bid&7 = ((hsub&1)<<2)|kvg -> each XCD serves ONE (b,kvh) KV panel
    int hsub = i >> 2, kvg = i & 3;
    int b = kvg >> 1, kvh = kvg & 1, h = kvh * 8 + hsub;
    int t = threadIdx.x, w = t >> 6, l = t & 63, g = l >> 4, lr = l & 15;
    int xk = lr & 7;
    const unsigned short* Kp = Kb + (size_t)(b * 2 + kvh) * S * 128;
    const unsigned short* Vp = Vt + (size_t)(b * 2 + kvh) * 128 * S;
    // staging geometry: 16 chunks of 1KB each for K and V; wave w owns chunks w*4..w*4+3
    int koff[4], voff[4], ldst[4];
    #pragma unroll
    for (int jj = 0; jj < 4; ++jj) {
        int c = w * 4 + jj;
        int r = c * 4 + (l >> 4);            // K row 0..63
        int ks = (l & 15) ^ (r & 7);         // pre-swizzled source slot
        koff[jj] = r * 128 + ks * 8;
        int rv = c * 8 + (l >> 3);           // V row (d) 0..127
        int vs = (l & 7) ^ (rv & 7);
        voff[jj] = rv * S + vs * 8;
        ldst[jj] = c * 512;
    }
    const unsigned short* Qp = Qb + ((size_t)(b * 16 + h) * S + qt * 128 + w * 32) * 128;
    bf16x8 qf[2][4];
    #pragma unroll
    for (int qs = 0; qs < 2; ++qs)
        #pragma unroll
        for (int ch = 0; ch < 4; ++ch)
            qf[qs][ch] = *(const bf16x8*)(Qp + (qs * 16 + lr) * 128 + ch * 32 + g * 8);
    f32x4 oacc[2][8] = {};
    float m_r[2][4] = {{-3e38f, -3e38f, -3e38f, -3e38f}, {-3e38f, -3e38f, -3e38f, -3e38f}};
    float l_r[2][4] = {{0.f, 0.f, 0.f, 0.f}, {0.f, 0.f, 0.f, 0.f}};
    int qlo = qt * 128 + w * 32;
    int nkt = 2 * qt + 2;
    // prologue: stage K(0) into buffer 0; wait own loads; barrier => K(0) resident for all
    #pragma unroll
    for (int jj = 0; jj < 4; ++jj)
        gload_lds16(Kp + koff[jj], Ks + ldst[jj]);
    asm volatile("s_waitcnt vmcnt(0)" ::: "memory");
    __builtin_amdgcn_s_barrier();
    int cur = 0;
    for (int kt = 0; kt < nkt; ++kt) {
        int k0 = kt * 64;
        bool more = (kt + 1 < nkt);
        // issue V(kt) -> Vs (consumed this tile after barrier A)
        #pragma unroll
        for (int jj = 0; jj < 4; ++jj)
            gload_lds16(Vp + (size_t)k0 + voff[jj], Vs + ldst[jj]);
        // issue K(kt+1) -> alternate buffer (consumed next tile)
        if (more) {
            const unsigned short* kb = Kp + (size_t)(k0 + 64) * 128;
            unsigned short* kd = Ks + (cur ^ 1) * 8192;
            #pragma unroll
            for (int jj = 0; jj < 4; ++jj)
                gload_lds16(kb + koff[jj], kd + ldst[jj]);
        }
        const unsigned short* Kc = Ks + cur * 8192;
        bool active = (k0 <= qlo + 31);
        if (active) {
            // ---- S = Q K^T (each kf read feeds 2 MFMAs) ----
            f32x4 sacc[2][4] = {};
            __builtin_amdgcn_s_setprio(1);
            #pragma unroll
            for (int nf = 0; nf < 4; ++nf) {
                int row = nf * 16 + lr;
                #pragma unroll
                for (int ch = 0; ch < 4; ++ch) {
                    bf16x8 kf = *(const bf16x8*)(Kc + row * 128 + (((ch * 4 + g) ^ xk) << 3));
                    sacc[0][nf] = MFMA16(qf[0][ch], kf, sacc[0][nf]);
                    sacc[1][nf] = MFMA16(qf[1][ch], kf, sacc[1][nf]);
                }
            }
            __builtin_amdgcn_s_setprio(0);
            // ---- online softmax ----
            bool diag = (k0 + 63 > qlo);
            #pragma unroll
            for (int qs = 0; qs < 2; ++qs) {
                #pragma unroll
                for (int r = 0; r < 4; ++r) {
                    int qg = qlo + qs * 16 + g * 4 + r;
                    float s0 = sacc[qs][0][r], s1 = sacc[qs][1][r];
                    float s2 = sacc[qs][2][r], s3 = sacc[qs][3][r];
                    if (diag) {
                        if (k0 + lr > qg) s0 = -1e30f;
                        if (k0 + 16 + lr > qg) s1 = -1e30f;
                        if (k0 + 32 + lr > qg) s2 = -1e30f;
                        if (k0 + 48 + lr > qg) s3 = -1e30f;
                    }
                    float mx = fmaxf(fmaxf(s0, s1), fmaxf(s2, s3));
                    mx = fmaxf(mx, __shfl_xor(mx, 1));
                    mx = fmaxf(mx, __shfl_xor(mx, 2));
                    mx = fmaxf(mx, __shfl_xor(mx, 4));
                    mx = fmaxf(mx, __shfl_xor(mx, 8));
                    float mnew = fmaxf(m_r[qs][r], mx);
                    float alpha = __expf(m_r[qs][r] - mnew);
                    float p0 = __expf(s0 - mnew), p1 = __expf(s1 - mnew);
                    float p2 = __expf(s2 - mnew), p3 = __expf(s3 - mnew);
                    float rs = (p0 + p1) + (p2 + p3);
                    rs += __shfl_xor(rs, 1);
                    rs += __shfl_xor(rs, 2);
                    rs += __shfl_xor(rs, 4);
                    rs += __shfl_xor(rs, 8);
                    l_r[qs][r] = l_r[qs][r] * alpha + rs;
                    m_r[qs][r] = mnew;
                    int prow = (qs * 16 + g * 4 + r) * PSTR + lr;
                    Pw[w][prow]      = f2bf(p0);
                    Pw[w][prow + 16] = f2bf(p1);
                    Pw[w][prow + 32] = f2bf(p2);
                    Pw[w][prow + 48] = f2bf(p3);
                    #pragma unroll
                    for (int df = 0; df < 8; ++df) oacc[qs][df][r] *= alpha;
                }
            }
        }
        // barrier A: own V(kt) landed (K(kt+1) still in flight) -> all waves' V resident
        if (more) asm volatile("s_waitcnt vmcnt(4) lgkmcnt(0)" ::: "memory");
        else      asm volatile("s_waitcnt vmcnt(0) lgkmcnt(0)" ::: "memory");
        __builtin_amdgcn_sched_barrier(0);
        __builtin_amdgcn_s_barrier();
        if (active) {
            // ---- O += P V (each vf read feeds 2 MFMAs) ----
            __builtin_amdgcn_s_setprio(1);
            #pragma unroll
            for (int ch2 = 0; ch2 < 2; ++ch2) {
                bf16x8 pf0 = *(const bf16x8*)(&Pw[w][lr * PSTR + ch2 * 32 + g * 8]);
                bf16x8 pf1 = *(const bf16x8*)(&Pw[w][(16 + lr) * PSTR + ch2 * 32 + g * 8]);
                #pragma unroll
                for (int df = 0; df < 8; ++df) {
                    int row = df * 16 + lr;
                    bf16x8 vf = *(const bf16x8*)(Vs + row * 64 + (((ch2 * 4 + g) ^ xk) << 3));
                    oacc[0][df] = MFMA16(pf0, vf, oacc[0][df]);
                    oacc[1][df] = MFMA16(pf1, vf, oacc[1][df]);
                }
            }
            __builtin_amdgcn_s_setprio(0);
        }
        // barrier B: K(kt+1) landed (covered by a whole tile of compute) -> safe to read next tile
        asm volatile("s_waitcnt vmcnt(0) lgkmcnt(0)" ::: "memory");
        __builtin_amdgcn_sched_barrier(0);
        __builtin_amdgcn_s_barrier();
        cur ^= 1;
    }
    // ---- epilogue ----
    #pragma unroll
    for (int qs = 0; qs < 2; ++qs) {
        #pragma unroll
        for (int r = 0; r < 4; ++r) {
            float inv = 1.0f / l_r[qs][r];
            size_t orow = ((size_t)b * S + qt * 128 + w * 32 + qs * 16 + g * 4 + r) * 2048 + h * 128;
            #pragma unroll
            for (int df = 0; df < 8; ++df)
                Ob[orow + df * 16 + lr] = f2bf(oacc[qs][df][r] * inv);
        }
    }
}

extern "C" void kernel_launch(void* const* d_in, const int* in_sizes, int n_in,
                              void* d_out, int out_size, void* d_ws, size_t ws_size,
                              hipStream_t stream) {
    const float* X    = (const float*)d_in[0];
    const float* cosp = (const float*)d_in[1];
    const float* sinp = (const float*)d_in[2];
    // d_in[3] = attention_mask (exactly causal; implemented analytically)
    const float* Wq = (const float*)d_in[4];
    const float* bq = (const float*)d_in[5];
    const float* Wk = (const float*)d_in[6];
    const float* bk = (const float*)d_in[7];
    const float* Wv = (const float*)d_in[8];
    const float* bv = (const float*)d_in[9];
    const float* Wo = (const float*)d_in[10];
    float* Out = (float*)d_out;

    char* ws = (char*)d_ws;
    unsigned short* Xb  = (unsigned short*)(ws + 0);
    unsigned short* Wt  = (unsigned short*)(ws + 16777216);
    unsigned short* Wot = (unsigned short*)(ws + 27262976);
    float*          Yq  = (float*)(ws + 35651584);
    unsigned short* Qb  = (unsigned short*)(ws + 0);
    unsigned short* Kb  = (unsigned short*)(ws + 16777216);   // 2 MB
    unsigned short* Vtb = (unsigned short*)(ws + 18874368);   // 2 MB ([4][128][2048])
    unsigned short* Ab  = (unsigned short*)(ws + 35651584);

    k_conv<<<2097152 / 256, 256, 0, stream>>>(X, Xb, 2097152);
    dim3 tb(32, 8);
    k_transpose<<<dim3(64, 64), tb, 0, stream>>>(Wq, Wt, 2048, 2048);
    k_transpose<<<dim3(8, 64), tb, 0, stream>>>(Wk, Wt + (size_t)2048 * 2048, 2048, 256);
    k_transpose<<<dim3(8, 64), tb, 0, stream>>>(Wv, Wt + (size_t)2304 * 2048, 2048, 256);
    k_transpose<<<dim3(64, 64), tb, 0, stream>>>(Wo, Wot, 2048, 2048);
    k_gemm<<<dim3(2560 / 128, 4096 / 128), 256, 0, stream>>>(Xb, Wt, Yq, 4096, 2560, 2048);
    k_pack<<<dim3(4096, 20), 128, 0, stream>>>(Yq, bq, bk, bv, cosp, sinp, Qb, Kb, Vtb);
    k_attn<<<dim3(512), 256, 0, stream>>>(Qb, Kb, Vtb, Ab);
    k_gemm<<<dim3(2048 / 128, 4096 / 128), 256, 0, stream>>>(Ab, Wot, Out, 4096, 2048, 2048);
}

// Round 8
// 253.426 us; speedup vs baseline: 1.2844x; 1.2432x over previous
//
#include <hip/hip_runtime.h>

typedef __attribute__((ext_vector_type(8))) short bf16x8;
typedef __attribute__((ext_vector_type(4))) float f32x4;

#define MFMA16(a, b, c) __builtin_amdgcn_mfma_f32_16x16x32_bf16(a, b, c, 0, 0, 0)

__device__ __forceinline__ unsigned short f2bf(float f) {
    union { float f; unsigned u; } v; v.f = f;
    unsigned r = v.u + 0x7FFFu + ((v.u >> 16) & 1u);
    return (unsigned short)(r >> 16);
}

typedef __attribute__((address_space(1))) const unsigned char gas1;
typedef __attribute__((address_space(3))) unsigned char las3;
__device__ __forceinline__ void gload_lds16(const void* g, void* s) {
    __builtin_amdgcn_global_load_lds((gas1*)g, (las3*)s, 16, 0, 0);
}

// ---------------- X fp32 -> bf16 (vectorized) ----------------
__global__ void k_conv(const float* __restrict__ in, unsigned short* __restrict__ out, int n4) {
    int i = blockIdx.x * blockDim.x + threadIdx.x;
    if (i >= n4) return;
    float4 v = ((const float4*)in)[i];
    uint2 o;
    o.x = (unsigned)f2bf(v.x) | ((unsigned)f2bf(v.y) << 16);
    o.y = (unsigned)f2bf(v.z) | ((unsigned)f2bf(v.w) << 16);
    ((uint2*)out)[i] = o;
}

// ---------------- W fp32 [R][C] -> bf16 [C][R] (LDS tiled transpose) ----------------
__global__ void k_transpose(const float* __restrict__ in, unsigned short* __restrict__ out, int R, int C) {
    __shared__ float tile[32][33];
    int bx = blockIdx.x * 32, by = blockIdx.y * 32;
    int tx = threadIdx.x, ty = threadIdx.y;
    #pragma unroll
    for (int j = 0; j < 32; j += 8)
        tile[ty + j][tx] = in[(size_t)(by + ty + j) * C + bx + tx];
    __syncthreads();
    #pragma unroll
    for (int j = 0; j < 32; j += 8)
        out[(size_t)(bx + ty + j) * R + by + tx] = f2bf(tile[tx][ty + j]);
}

// ---------------- GEMM (m97 structure): C[M][N] = A[M][K] * Bt[N][K], bf16 in fp32 out ----
__global__ __launch_bounds__(256) void k_gemm(const unsigned short* __restrict__ A,
                                              const unsigned short* __restrict__ Bt,
                                              float* __restrict__ C, int M, int N, int K) {
    __shared__ __align__(16) unsigned short As[128 * 32];
    __shared__ __align__(16) unsigned short Bs[128 * 32];
    int t = threadIdx.x, w = t >> 6, l = t & 63, g = l >> 4, lr = l & 15;
    int m0 = blockIdx.y * 128, n0 = blockIdx.x * 128;
    int wm = (w >> 1) * 64, wn = (w & 1) * 64;
    f32x4 acc[4][4] = {};
    int c0 = w * 2, c1 = w * 2 + 1;
    int srow0 = c0 * 16 + (l >> 2), srow1 = c1 * 16 + (l >> 2);
    int scol = (l & 3) * 8;
    const unsigned short* Ag0 = A + (size_t)(m0 + srow0) * K + scol;
    const unsigned short* Ag1 = A + (size_t)(m0 + srow1) * K + scol;
    const unsigned short* Bg0 = Bt + (size_t)(n0 + srow0) * K + scol;
    const unsigned short* Bg1 = Bt + (size_t)(n0 + srow1) * K + scol;
    unsigned short* Ad0 = As + c0 * 512;
    unsigned short* Ad1 = As + c1 * 512;
    unsigned short* Bd0 = Bs + c0 * 512;
    unsigned short* Bd1 = Bs + c1 * 512;
    for (int k0 = 0; k0 < K; k0 += 32) {
        __syncthreads();
        gload_lds16(Ag0 + k0, Ad0);
        gload_lds16(Ag1 + k0, Ad1);
        gload_lds16(Bg0 + k0, Bd0);
        gload_lds16(Bg1 + k0, Bd1);
        __syncthreads();
        bf16x8 af[4], bfr[4];
        #pragma unroll
        for (int f = 0; f < 4; ++f) {
            af[f] = *(const bf16x8*)(As + (wm + f * 16 + lr) * 32 + g * 8);
            bfr[f] = *(const bf16x8*)(Bs + (wn + f * 16 + lr) * 32 + g * 8);
        }
        #pragma unroll
        for (int mf = 0; mf < 4; ++mf)
            #pragma unroll
            for (int nf = 0; nf < 4; ++nf)
                acc[mf][nf] = MFMA16(af[mf], bfr[nf], acc[mf][nf]);
    }
    #pragma unroll
    for (int mf = 0; mf < 4; ++mf)
        #pragma unroll
        for (int nf = 0; nf < 4; ++nf)
            #pragma unroll
            for (int r = 0; r < 4; ++r)
                C[(size_t)(m0 + wm + mf * 16 + g * 4 + r) * N + (n0 + wn + nf * 16 + lr)] = acc[mf][nf][r];
}

// ---------------- bias + RoPE + layout pack ----------------
__global__ void k_pack(const float* __restrict__ Y, const float* __restrict__ bq,
                       const float* __restrict__ bk, const float* __restrict__ bv,
                       const float* __restrict__ cosp, const float* __restrict__ sinp,
                       unsigned short* __restrict__ Qb, unsigned short* __restrict__ Kb,
                       unsigned short* __restrict__ Vt) {
    const int S = 2048;
    int row = blockIdx.x;      // b*S + s
    int hh = blockIdx.y;       // 0..15 Q, 16..17 K, 18..19 V
    int d = threadIdx.x;       // 0..127
    int b = row >> 11, s = row & 2047;
    const float* yrow = Y + (size_t)row * 2560;
    if (hh < 16) {
        const float* base = yrow + hh * 128;
        const float* bias = bq + hh * 128;
        float self = base[d] + bias[d];
        int pd = (d < 64) ? d + 64 : d - 64;
        float partner = base[pd] + bias[pd];
        float rot = (d < 64) ? -partner : partner;
        float c = cosp[(size_t)row * 128 + d];
        float sn = sinp[(size_t)row * 128 + d];
        float q = (self * c + rot * sn) * 0.08838834764831845f;
        Qb[((size_t)(b * 16 + hh) * S + s) * 128 + d] = f2bf(q);
    } else if (hh < 18) {
        int kv = hh - 16;
        const float* base = yrow + 2048 + kv * 128;
        const float* bias = bk + kv * 128;
        float self = base[d] + bias[d];
        int pd = (d < 64) ? d + 64 : d - 64;
        float partner = base[pd] + bias[pd];
        float rot = (d < 64) ? -partner : partner;
        float c = cosp[(size_t)row * 128 + d];
        float sn = sinp[(size_t)row * 128 + d];
        float k = self * c + rot * sn;
        Kb[((size_t)(b * 2 + kv) * S + s) * 128 + d] = f2bf(k);
    } else {
        int kv = hh - 18;
        float v = yrow[2304 + kv * 128 + d] + bv[kv * 128 + d];
        Vt[((size_t)(b * 2 + kv) * 128 + d) * S + s] = f2bf(v);
    }
}

// ---------------- flash attention v8 ----------------
// r5 decomposition (proven 101us): 512 uniform blocks = 16 pairs x 16 h x 2 b, XCD-grouped;
// block does q-tiles {p, 31-p} sequentially (33 kv-tiles, perfectly balanced); 4 waves x 16 rows.
// New: counted-vmcnt raw barriers (no idle drains), deferred l-sum (half the shuffles),
// V single-buffered, P stride 72 (16B-aligned pf reads). LDS 57.6KB -> 2 blocks/CU.
#define PSTR 72
__global__ __launch_bounds__(256, 2) void k_attn(const unsigned short* __restrict__ Qb,
                                                 const unsigned short* __restrict__ Kb,
                                                 const unsigned short* __restrict__ Vt,
                                                 unsigned short* __restrict__ Ob) {
    const int S = 2048;
    __shared__ __align__(16) unsigned short Ks[2 * 64 * 128];   // 32 KB (double-buffered)
    __shared__ __align__(16) unsigned short Vs[128 * 64];       // 16 KB (single)
    __shared__ __align__(16) unsigned short Pw[4][16 * PSTR];   // 9.2 KB
    int bid = blockIdx.x;
    int xcd = bid & 7, j = bid >> 3;
    int G = (j >> 4) * 8 + xcd;          // 0..31: (h,b) group, XCD-contiguous
    int pair = j & 15;
    int h = G & 15, b = G >> 4;
    int kvh = h >> 3;
    int t = threadIdx.x, w = t >> 6, l = t & 63, g = l >> 4, lr = l & 15;
    int xk = lr & 7;
    const unsigned short* Kp = Kb + (size_t)(b * 2 + kvh) * S * 128;
    const unsigned short* Vp = Vt + (size_t)(b * 2 + kvh) * 128 * S;
    // staging: 16 chunks of 1KB each for K and V; wave w owns chunks w*4..w*4+3
    int koff[4], voff[4], ldst[4];
    #pragma unroll
    for (int jj = 0; jj < 4; ++jj) {
        int c = w * 4 + jj;
        int r = c * 4 + (l >> 4);            // K row 0..63
        int ks = (l & 15) ^ (r & 7);         // pre-swizzled source slot
        koff[jj] = r * 128 + ks * 8;
        int rv = c * 8 + (l >> 3);           // V row (d) 0..127
        int vs = (l & 7) ^ (rv & 7);
        voff[jj] = rv * S + vs * 8;
        ldst[jj] = c * 512;
    }
    int cur = 0;
    #pragma unroll
    for (int half = 0; half < 2; ++half) {
        int qt = half == 0 ? pair : 31 - pair;
        const unsigned short* Qp = Qb + ((size_t)(b * 16 + h) * S + qt * 64 + w * 16) * 128;
        bf16x8 qf[4];
        #pragma unroll
        for (int ch = 0; ch < 4; ++ch)
            qf[ch] = *(const bf16x8*)(Qp + lr * 128 + ch * 32 + g * 8);
        f32x4 oacc[8] = {};
        float m_r[4] = {-3e38f, -3e38f, -3e38f, -3e38f};
        float l_r[4] = {0.f, 0.f, 0.f, 0.f};   // per-lane partial sums (reduced in epilogue)
        int qlo = qt * 64 + w * 16;
        // prologue: stage K(0) into Ks[cur]; drain everything (incl. qf) so vmcnt counts are exact
        #pragma unroll
        for (int jj = 0; jj < 4; ++jj)
            gload_lds16(Kp + koff[jj], Ks + cur * 8192 + ldst[jj]);
        asm volatile("s_waitcnt vmcnt(0)" ::: "memory");
        __builtin_amdgcn_s_barrier();
        for (int kt = 0; kt <= qt; ++kt) {
            int k0 = kt * 64;
            bool more = kt < qt;
            // issue V(kt) -> Vs (4 loads), then K(kt+1) -> alternate K buffer (4 loads)
            #pragma unroll
            for (int jj = 0; jj < 4; ++jj)
                gload_lds16(Vp + (size_t)k0 + voff[jj], Vs + ldst[jj]);
            if (more) {
                const unsigned short* kb = Kp + (size_t)(k0 + 64) * 128;
                unsigned short* kd = Ks + (cur ^ 1) * 8192;
                #pragma unroll
                for (int jj = 0; jj < 4; ++jj)
                    gload_lds16(kb + koff[jj], kd + ldst[jj]);
            }
            const unsigned short* Kc = Ks + cur * 8192;
            // ---- S = Q K^T ----
            f32x4 sacc[4] = {};
            __builtin_amdgcn_s_setprio(1);
            #pragma unroll
            for (int nf = 0; nf < 4; ++nf) {
                int row = nf * 16 + lr;
                #pragma unroll
                for (int ch = 0; ch < 4; ++ch) {
                    bf16x8 kf = *(const bf16x8*)(Kc + row * 128 + (((ch * 4 + g) ^ xk) << 3));
                    sacc[nf] = MFMA16(qf[ch], kf, sacc[nf]);
                }
            }
            __builtin_amdgcn_s_setprio(0);
            // ---- online softmax (mask only on the diagonal tile; l-sum deferred) ----
            bool diag = (kt == qt);
            #pragma unroll
            for (int r = 0; r < 4; ++r) {
                int qg = qlo + g * 4 + r;
                float s0 = sacc[0][r], s1 = sacc[1][r], s2 = sacc[2][r], s3 = sacc[3][r];
                if (diag) {
                    if (k0 + lr > qg) s0 = -1e30f;
                    if (k0 + 16 + lr > qg) s1 = -1e30f;
                    if (k0 + 32 + lr > qg) s2 = -1e30f;
                    if (k0 + 48 + lr > qg) s3 = -1e30f;
                }
                float mx = fmaxf(fmaxf(s0, s1), fmaxf(s2, s3));
                mx = fmaxf(mx, __shfl_xor(mx, 1));
                mx = fmaxf(mx, __shfl_xor(mx, 2));
                mx = fmaxf(mx, __shfl_xor(mx, 4));
                mx = fmaxf(mx, __shfl_xor(mx, 8));
                float mnew = fmaxf(m_r[r], mx);
                float alpha = __expf(m_r[r] - mnew);
                float p0 = __expf(s0 - mnew), p1 = __expf(s1 - mnew);
                float p2 = __expf(s2 - mnew), p3 = __expf(s3 - mnew);
                l_r[r] = l_r[r] * alpha + ((p0 + p1) + (p2 + p3));  // per-lane partial
                m_r[r] = mnew;
                int prow = (g * 4 + r) * PSTR + lr;
                Pw[w][prow]      = f2bf(p0);
                Pw[w][prow + 16] = f2bf(p1);
                Pw[w][prow + 32] = f2bf(p2);
                Pw[w][prow + 48] = f2bf(p3);
                #pragma unroll
                for (int df = 0; df < 8; ++df) oacc[df][r] *= alpha;
            }
            // barrier A: own V(kt) landed (K(kt+1) still in flight); P writes drained
            if (more) asm volatile("s_waitcnt vmcnt(4) lgkmcnt(0)" ::: "memory");
            else      asm volatile("s_waitcnt vmcnt(0) lgkmcnt(0)" ::: "memory");
            __builtin_amdgcn_sched_barrier(0);
            __builtin_amdgcn_s_barrier();
            // ---- O += P V ----
            __builtin_amdgcn_s_setprio(1);
            #pragma unroll
            for (int ch2 = 0; ch2 < 2; ++ch2) {
                bf16x8 pf = *(const bf16x8*)(&Pw[w][lr * PSTR + ch2 * 32 + g * 8]);
                #pragma unroll
                for (int df = 0; df < 8; ++df) {
                    int row = df * 16 + lr;
                    bf16x8 vf = *(const bf16x8*)(Vs + row * 64 + (((ch2 * 4 + g) ^ xk) << 3));
                    oacc[df] = MFMA16(pf, vf, oacc[df]);
                }
            }
            __builtin_amdgcn_s_setprio(0);
            // barrier B: K(kt+1) landed (covered by this tile's compute); Vs readers done
            asm volatile("s_waitcnt vmcnt(0)" ::: "memory");
            __builtin_amdgcn_sched_barrier(0);
            __builtin_amdgcn_s_barrier();
            cur ^= 1;
        }
        // ---- epilogue: reduce deferred l across the 16-lane groups, normalize, store ----
        #pragma unroll
        for (int r = 0; r < 4; ++r) {
            float ls = l_r[r];
            ls += __shfl_xor(ls, 1);
            ls += __shfl_xor(ls, 2);
            ls += __shfl_xor(ls, 4);
            ls += __shfl_xor(ls, 8);
            float inv = 1.0f / ls;
            size_t orow = ((size_t)b * S + qt * 64 + w * 16 + g * 4 + r) * 2048 + h * 128;
            #pragma unroll
            for (int df = 0; df < 8; ++df)
                Ob[orow + df * 16 + lr] = f2bf(oacc[df][r] * inv);
        }
    }
}

extern "C" void kernel_launch(void* const* d_in, const int* in_sizes, int n_in,
                              void* d_out, int out_size, void* d_ws, size_t ws_size,
                              hipStream_t stream) {
    const float* X    = (const float*)d_in[0];
    const float* cosp = (const float*)d_in[1];
    const float* sinp = (const float*)d_in[2];
    // d_in[3] = attention_mask (exactly causal; implemented analytically)
    const float* Wq = (const float*)d_in[4];
    const float* bq = (const float*)d_in[5];
    const float* Wk = (const float*)d_in[6];
    const float* bk = (const float*)d_in[7];
    const float* Wv = (const float*)d_in[8];
    const float* bv = (const float*)d_in[9];
    const float* Wo = (const float*)d_in[10];
    float* Out = (float*)d_out;

    char* ws = (char*)d_ws;
    unsigned short* Xb  = (unsigned short*)(ws + 0);
    unsigned short* Wt  = (unsigned short*)(ws + 16777216);
    unsigned short* Wot = (unsigned short*)(ws + 27262976);
    float*          Yq  = (float*)(ws + 35651584);
    unsigned short* Qb  = (unsigned short*)(ws + 0);
    unsigned short* Kb  = (unsigned short*)(ws + 16777216);   // 2 MB
    unsigned short* Vtb = (unsigned short*)(ws + 18874368);   // 2 MB ([4][128][2048])
    unsigned short* Ab  = (unsigned short*)(ws + 35651584);

    k_conv<<<2097152 / 256, 256, 0, stream>>>(X, Xb, 2097152);
    dim3 tb(32, 8);
    k_transpose<<<dim3(64, 64), tb, 0, stream>>>(Wq, Wt, 2048, 2048);
    k_transpose<<<dim3(8, 64), tb, 0, stream>>>(Wk, Wt + (size_t)2048 * 2048, 2048, 256);
    k_transpose<<<dim3(8, 64), tb, 0, stream>>>(Wv, Wt + (size_t)2304 * 2048, 2048, 256);
    k_transpose<<<dim3(64, 64), tb, 0, stream>>>(Wo, Wot, 2048, 2048);
    k_gemm<<<dim3(2560 / 128, 4096 / 128), 256, 0, stream>>>(Xb, Wt, Yq, 4096, 2560, 2048);
    k_pack<<<dim3(4096, 20), 128, 0, stream>>>(Yq, bq, bk, bv, cosp, sinp, Qb, Kb, Vtb);
    k_attn<<<dim3(512), 256, 0, stream>>>(Qb, Kb, Vtb, Ab);
    k_gemm<<<dim3(2048 / 128, 4096 / 128), 256, 0, stream>>>(Ab, Wot, Out, 4096, 2048, 2048);
}

// Round 9
// 245.562 us; speedup vs baseline: 1.3255x; 1.0320x over previous
//
#include <hip/hip_runtime.h>

typedef __attribute__((ext_vector_type(8))) short bf16x8;
typedef __attribute__((ext_vector_type(4))) float f32x4;

#define MFMA16(a, b, c) __builtin_amdgcn_mfma_f32_16x16x32_bf16(a, b, c, 0, 0, 0)

__device__ __forceinline__ unsigned short f2bf(float f) {
    union { float f; unsigned u; } v; v.f = f;
    unsigned r = v.u + 0x7FFFu + ((v.u >> 16) & 1u);
    return (unsigned short)(r >> 16);
}
__device__ __forceinline__ float bf2f(unsigned short u) {
    union { unsigned u; float f; } v; v.u = ((unsigned)u) << 16;
    return v.f;
}

typedef __attribute__((address_space(1))) const unsigned char gas1;
typedef __attribute__((address_space(3))) unsigned char las3;
__device__ __forceinline__ void gload_lds16(const void* g, void* s) {
    __builtin_amdgcn_global_load_lds((gas1*)g, (las3*)s, 16, 0, 0);
}

// ---------------- X fp32 -> bf16 (vectorized) ----------------
__global__ void k_conv(const float* __restrict__ in, unsigned short* __restrict__ out, int n4) {
    int i = blockIdx.x * blockDim.x + threadIdx.x;
    if (i >= n4) return;
    float4 v = ((const float4*)in)[i];
    uint2 o;
    o.x = (unsigned)f2bf(v.x) | ((unsigned)f2bf(v.y) << 16);
    o.y = (unsigned)f2bf(v.z) | ((unsigned)f2bf(v.w) << 16);
    ((uint2*)out)[i] = o;
}

// ---------------- W fp32 [R][C] -> bf16 [C][R] (LDS tiled transpose) ----------------
__global__ void k_transpose(const float* __restrict__ in, unsigned short* __restrict__ out, int R, int C) {
    __shared__ float tile[32][33];
    int bx = blockIdx.x * 32, by = blockIdx.y * 32;
    int tx = threadIdx.x, ty = threadIdx.y;
    #pragma unroll
    for (int j = 0; j < 32; j += 8)
        tile[ty + j][tx] = in[(size_t)(by + ty + j) * C + bx + tx];
    __syncthreads();
    #pragma unroll
    for (int j = 0; j < 32; j += 8)
        out[(size_t)(bx + ty + j) * R + by + tx] = f2bf(tile[tx][ty + j]);
}

// ---------------- GEMM (m97 structure): C[M][N] = A[M][K] * Bt[N][K], bf16 in ----
// OBF16=0: fp32 out; OBF16=1: bf16 out.
template<int OBF16>
__global__ __launch_bounds__(256) void k_gemm(const unsigned short* __restrict__ A,
                                              const unsigned short* __restrict__ Bt,
                                              void* __restrict__ Cv, int M, int N, int K) {
    __shared__ __align__(16) unsigned short As[128 * 32];
    __shared__ __align__(16) unsigned short Bs[128 * 32];
    int t = threadIdx.x, w = t >> 6, l = t & 63, g = l >> 4, lr = l & 15;
    int m0 = blockIdx.y * 128, n0 = blockIdx.x * 128;
    int wm = (w >> 1) * 64, wn = (w & 1) * 64;
    f32x4 acc[4][4] = {};
    int c0 = w * 2, c1 = w * 2 + 1;
    int srow0 = c0 * 16 + (l >> 2), srow1 = c1 * 16 + (l >> 2);
    int scol = (l & 3) * 8;
    const unsigned short* Ag0 = A + (size_t)(m0 + srow0) * K + scol;
    const unsigned short* Ag1 = A + (size_t)(m0 + srow1) * K + scol;
    const unsigned short* Bg0 = Bt + (size_t)(n0 + srow0) * K + scol;
    const unsigned short* Bg1 = Bt + (size_t)(n0 + srow1) * K + scol;
    unsigned short* Ad0 = As + c0 * 512;
    unsigned short* Ad1 = As + c1 * 512;
    unsigned short* Bd0 = Bs + c0 * 512;
    unsigned short* Bd1 = Bs + c1 * 512;
    for (int k0 = 0; k0 < K; k0 += 32) {
        __syncthreads();
        gload_lds16(Ag0 + k0, Ad0);
        gload_lds16(Ag1 + k0, Ad1);
        gload_lds16(Bg0 + k0, Bd0);
        gload_lds16(Bg1 + k0, Bd1);
        __syncthreads();
        bf16x8 af[4], bfr[4];
        #pragma unroll
        for (int f = 0; f < 4; ++f) {
            af[f] = *(const bf16x8*)(As + (wm + f * 16 + lr) * 32 + g * 8);
            bfr[f] = *(const bf16x8*)(Bs + (wn + f * 16 + lr) * 32 + g * 8);
        }
        #pragma unroll
        for (int mf = 0; mf < 4; ++mf)
            #pragma unroll
            for (int nf = 0; nf < 4; ++nf)
                acc[mf][nf] = MFMA16(af[mf], bfr[nf], acc[mf][nf]);
    }
    #pragma unroll
    for (int mf = 0; mf < 4; ++mf)
        #pragma unroll
        for (int nf = 0; nf < 4; ++nf)
            #pragma unroll
            for (int r = 0; r < 4; ++r) {
                size_t idx = (size_t)(m0 + wm + mf * 16 + g * 4 + r) * N + (n0 + wn + nf * 16 + lr);
                if (OBF16) ((unsigned short*)Cv)[idx] = f2bf(acc[mf][nf][r]);
                else       ((float*)Cv)[idx] = acc[mf][nf][r];
            }
}

// ---------------- bias + RoPE + layout pack (Y now bf16) ----------------
__global__ void k_pack(const unsigned short* __restrict__ Y, const float* __restrict__ bq,
                       const float* __restrict__ bk, const float* __restrict__ bv,
                       const float* __restrict__ cosp, const float* __restrict__ sinp,
                       unsigned short* __restrict__ Qb, unsigned short* __restrict__ Kb,
                       unsigned short* __restrict__ Vt) {
    const int S = 2048;
    int row = blockIdx.x;      // b*S + s
    int hh = blockIdx.y;       // 0..15 Q, 16..17 K, 18..19 V
    int d = threadIdx.x;       // 0..127
    int b = row >> 11, s = row & 2047;
    const unsigned short* yrow = Y + (size_t)row * 2560;
    if (hh < 16) {
        const unsigned short* base = yrow + hh * 128;
        const float* bias = bq + hh * 128;
        float self = bf2f(base[d]) + bias[d];
        int pd = (d < 64) ? d + 64 : d - 64;
        float partner = bf2f(base[pd]) + bias[pd];
        float rot = (d < 64) ? -partner : partner;
        float c = cosp[(size_t)row * 128 + d];
        float sn = sinp[(size_t)row * 128 + d];
        float q = (self * c + rot * sn) * 0.08838834764831845f;
        Qb[((size_t)(b * 16 + hh) * S + s) * 128 + d] = f2bf(q);
    } else if (hh < 18) {
        int kv = hh - 16;
        const unsigned short* base = yrow + 2048 + kv * 128;
        const float* bias = bk + kv * 128;
        float self = bf2f(base[d]) + bias[d];
        int pd = (d < 64) ? d + 64 : d - 64;
        float partner = bf2f(base[pd]) + bias[pd];
        float rot = (d < 64) ? -partner : partner;
        float c = cosp[(size_t)row * 128 + d];
        float sn = sinp[(size_t)row * 128 + d];
        float k = self * c + rot * sn;
        Kb[((size_t)(b * 2 + kv) * S + s) * 128 + d] = f2bf(k);
    } else {
        int kv = hh - 18;
        float v = bf2f(yrow[2304 + kv * 128 + d]) + bv[kv * 128 + d];
        Vt[((size_t)(b * 2 + kv) * 128 + d) * S + s] = f2bf(v);
    }
}

// ---------------- flash attention v9: single-barrier 2-phase pipeline ----------------
// v8 decomposition (512 uniform blocks, in-block pair {p,31-p}, 33 kv-tiles, 4 waves x 16 rows)
// + K AND V double-buffered; per tile: {vmcnt(0)[free] -> s_barrier -> issue next tile -> QK ->
// softmax -> PV}. One barrier/tile; P is per-wave (no cross-wave hazard). LDS 74.75KB, 2 blk/CU.
#define PSTR 72
__global__ __launch_bounds__(256, 2) void k_attn(const unsigned short* __restrict__ Qb,
                                                 const unsigned short* __restrict__ Kb,
                                                 const unsigned short* __restrict__ Vt,
                                                 unsigned short* __restrict__ Ob) {
    const int S = 2048;
    __shared__ __align__(16) unsigned short Ks[2 * 64 * 128];   // 32 KB dbuf
    __shared__ __align__(16) unsigned short Vs[2 * 128 * 64];   // 32 KB dbuf
    __shared__ __align__(16) unsigned short Pw[4][16 * PSTR];   // 9.2 KB
    int bid = blockIdx.x;
    int xcd = bid & 7, j = bid >> 3;
    int G = (j >> 4) * 8 + xcd;          // 0..31: (h,b) group, XCD-contiguous
    int pair = j & 15;
    int h = G & 15, b = G >> 4;
    int kvh = h >> 3;
    int t = threadIdx.x, w = t >> 6, l = t & 63, g = l >> 4, lr = l & 15;
    int xk = lr & 7;
    const unsigned short* Kp = Kb + (size_t)(b * 2 + kvh) * S * 128;
    const unsigned short* Vp = Vt + (size_t)(b * 2 + kvh) * 128 * S;
    // staging: 16 chunks of 1KB each for K and V; wave w owns chunks w*4..w*4+3
    int koff[4], voff[4], ldst[4];
    #pragma unroll
    for (int jj = 0; jj < 4; ++jj) {
        int c = w * 4 + jj;
        int r = c * 4 + (l >> 4);            // K row 0..63
        int ks = (l & 15) ^ (r & 7);         // pre-swizzled source slot
        koff[jj] = r * 128 + ks * 8;
        int rv = c * 8 + (l >> 3);           // V row (d) 0..127
        int vs = (l & 7) ^ (rv & 7);
        voff[jj] = rv * S + vs * 8;
        ldst[jj] = c * 512;
    }
    int cur = 0;
    #pragma unroll
    for (int half = 0; half < 2; ++half) {
        int qt = half == 0 ? pair : 31 - pair;
        const unsigned short* Qp = Qb + ((size_t)(b * 16 + h) * S + qt * 64 + w * 16) * 128;
        bf16x8 qf[4];
        #pragma unroll
        for (int ch = 0; ch < 4; ++ch)
            qf[ch] = *(const bf16x8*)(Qp + lr * 128 + ch * 32 + g * 8);
        f32x4 oacc[8] = {};
        float m_r[4] = {-3e38f, -3e38f, -3e38f, -3e38f};
        float l_r[4] = {0.f, 0.f, 0.f, 0.f};   // per-lane partials (reduced in epilogue)
        int qlo = qt * 64 + w * 16;
        // prologue: stage tile 0 into buf `cur` (safe: prior readers of this buf
        // finished before the last iteration's top barrier of the previous half)
        #pragma unroll
        for (int jj = 0; jj < 4; ++jj) {
            gload_lds16(Kp + koff[jj], Ks + cur * 8192 + ldst[jj]);
            gload_lds16(Vp + voff[jj], Vs + cur * 8192 + ldst[jj]);
        }
        for (int kt = 0; kt <= qt; ++kt) {
            int k0 = kt * 64;
            // own tile-kt chunks (issued a full iteration ago) landed; then publish to block
            asm volatile("s_waitcnt vmcnt(0)" ::: "memory");
            __builtin_amdgcn_s_barrier();
            // issue tile kt+1 into the alternate buffers (a full iteration of cover)
            if (kt < qt) {
                const unsigned short* kb = Kp + (size_t)(k0 + 64) * 128;
                const unsigned short* vb = Vp + (size_t)(k0 + 64);
                unsigned short* kd = Ks + (cur ^ 1) * 8192;
                unsigned short* vd = Vs + (cur ^ 1) * 8192;
                #pragma unroll
                for (int jj = 0; jj < 4; ++jj) {
                    gload_lds16(kb + koff[jj], kd + ldst[jj]);
                    gload_lds16(vb + voff[jj], vd + ldst[jj]);
                }
            }
            const unsigned short* Kc = Ks + cur * 8192;
            const unsigned short* Vc = Vs + cur * 8192;
            // ---- S = Q K^T ----
            f32x4 sacc[4] = {};
            __builtin_amdgcn_s_setprio(1);
            #pragma unroll
            for (int nf = 0; nf < 4; ++nf) {
                int row = nf * 16 + lr;
                #pragma unroll
                for (int ch = 0; ch < 4; ++ch) {
                    bf16x8 kf = *(const bf16x8*)(Kc + row * 128 + (((ch * 4 + g) ^ xk) << 3));
                    sacc[nf] = MFMA16(qf[ch], kf, sacc[nf]);
                }
            }
            __builtin_amdgcn_s_setprio(0);
            // ---- online softmax (mask only on diagonal tile; l-sum deferred) ----
            bool diag = (kt == qt);
            #pragma unroll
            for (int r = 0; r < 4; ++r) {
                int qg = qlo + g * 4 + r;
                float s0 = sacc[0][r], s1 = sacc[1][r], s2 = sacc[2][r], s3 = sacc[3][r];
                if (diag) {
                    if (k0 + lr > qg) s0 = -1e30f;
                    if (k0 + 16 + lr > qg) s1 = -1e30f;
                    if (k0 + 32 + lr > qg) s2 = -1e30f;
                    if (k0 + 48 + lr > qg) s3 = -1e30f;
                }
                float mx = fmaxf(fmaxf(s0, s1), fmaxf(s2, s3));
                mx = fmaxf(mx, __shfl_xor(mx, 1));
                mx = fmaxf(mx, __shfl_xor(mx, 2));
                mx = fmaxf(mx, __shfl_xor(mx, 4));
                mx = fmaxf(mx, __shfl_xor(mx, 8));
                float mnew = fmaxf(m_r[r], mx);
                float alpha = __expf(m_r[r] - mnew);
                float p0 = __expf(s0 - mnew), p1 = __expf(s1 - mnew);
                float p2 = __expf(s2 - mnew), p3 = __expf(s3 - mnew);
                l_r[r] = l_r[r] * alpha + ((p0 + p1) + (p2 + p3));
                m_r[r] = mnew;
                int prow = (g * 4 + r) * PSTR + lr;
                Pw[w][prow]      = f2bf(p0);
                Pw[w][prow + 16] = f2bf(p1);
                Pw[w][prow + 32] = f2bf(p2);
                Pw[w][prow + 48] = f2bf(p3);
                #pragma unroll
                for (int df = 0; df < 8; ++df) oacc[df][r] *= alpha;
            }
            // ---- O += P V (P write->read is same-wave; compiler orders via lgkmcnt) ----
            __builtin_amdgcn_s_setprio(1);
            #pragma unroll
            for (int ch2 = 0; ch2 < 2; ++ch2) {
                bf16x8 pf = *(const bf16x8*)(&Pw[w][lr * PSTR + ch2 * 32 + g * 8]);
                #pragma unroll
                for (int df = 0; df < 8; ++df) {
                    int row = df * 16 + lr;
                    bf16x8 vf = *(const bf16x8*)(Vc + row * 64 + (((ch2 * 4 + g) ^ xk) << 3));
                    oacc[df] = MFMA16(pf, vf, oacc[df]);
                }
            }
            __builtin_amdgcn_s_setprio(0);
            cur ^= 1;
        }
        // ---- epilogue: reduce deferred l, normalize, store ----
        #pragma unroll
        for (int r = 0; r < 4; ++r) {
            float ls = l_r[r];
            ls += __shfl_xor(ls, 1);
            ls += __shfl_xor(ls, 2);
            ls += __shfl_xor(ls, 4);
            ls += __shfl_xor(ls, 8);
            float inv = 1.0f / ls;
            size_t orow = ((size_t)b * S + qt * 64 + w * 16 + g * 4 + r) * 2048 + h * 128;
            #pragma unroll
            for (int df = 0; df < 8; ++df)
                Ob[orow + df * 16 + lr] = f2bf(oacc[df][r] * inv);
        }
    }
}

extern "C" void kernel_launch(void* const* d_in, const int* in_sizes, int n_in,
                              void* d_out, int out_size, void* d_ws, size_t ws_size,
                              hipStream_t stream) {
    const float* X    = (const float*)d_in[0];
    const float* cosp = (const float*)d_in[1];
    const float* sinp = (const float*)d_in[2];
    // d_in[3] = attention_mask (exactly causal; implemented analytically)
    const float* Wq = (const float*)d_in[4];
    const float* bq = (const float*)d_in[5];
    const float* Wk = (const float*)d_in[6];
    const float* bk = (const float*)d_in[7];
    const float* Wv = (const float*)d_in[8];
    const float* bv = (const float*)d_in[9];
    const float* Wo = (const float*)d_in[10];
    float* Out = (float*)d_out;

    char* ws = (char*)d_ws;
    unsigned short* Xb  = (unsigned short*)(ws + 0);
    unsigned short* Wt  = (unsigned short*)(ws + 16777216);
    unsigned short* Wot = (unsigned short*)(ws + 27262976);
    unsigned short* Yqb = (unsigned short*)(ws + 35651584);   // bf16 [4096][2560] = 20 MB
    unsigned short* Qb  = (unsigned short*)(ws + 0);
    unsigned short* Kb  = (unsigned short*)(ws + 16777216);   // 2 MB
    unsigned short* Vtb = (unsigned short*)(ws + 18874368);   // 2 MB ([4][128][2048])
    unsigned short* Ab  = (unsigned short*)(ws + 56623104);   // 16 MB (after Yqb)

    k_conv<<<2097152 / 256, 256, 0, stream>>>(X, Xb, 2097152);
    dim3 tb(32, 8);
    k_transpose<<<dim3(64, 64), tb, 0, stream>>>(Wq, Wt, 2048, 2048);
    k_transpose<<<dim3(8, 64), tb, 0, stream>>>(Wk, Wt + (size_t)2048 * 2048, 2048, 256);
    k_transpose<<<dim3(8, 64), tb, 0, stream>>>(Wv, Wt + (size_t)2304 * 2048, 2048, 256);
    k_transpose<<<dim3(64, 64), tb, 0, stream>>>(Wo, Wot, 2048, 2048);
    k_gemm<1><<<dim3(2560 / 128, 4096 / 128), 256, 0, stream>>>(Xb, Wt, Yqb, 4096, 2560, 2048);
    k_pack<<<dim3(4096, 20), 128, 0, stream>>>(Yqb, bq, bk, bv, cosp, sinp, Qb, Kb, Vtb);
    k_attn<<<dim3(512), 256, 0, stream>>>(Qb, Kb, Vtb, Ab);
    k_gemm<0><<<dim3(2048 / 128, 4096 / 128), 256, 0, stream>>>(Ab, Wot, Out, 4096, 2048, 2048);
}